// Round 7
// baseline (507.775 us; speedup 1.0000x reference)
//
#include <hip/hip_runtime.h>
#include <hip/hip_bf16.h>

#define BDIM 256
constexpr int Bc = 4, Hc = 128, Wcn = 128, Cc = 768, WM = 65, NB = 8, BS = 96;
constexpr int NROWS = Bc * WM * Hc;              // 33280 spectral rows (b, wm, h)
constexpr size_t NSPEC = (size_t)NROWS * Cc;     // 25,559,040 elems per r/i plane

typedef __attribute__((ext_vector_type(8))) _Float16 f16x8;
typedef __attribute__((ext_vector_type(4))) float f32x4;
typedef __attribute__((ext_vector_type(4))) unsigned int u32x4;

__device__ __forceinline__ unsigned short f2h(float f) {
    return __builtin_bit_cast(unsigned short, (_Float16)f);
}
__device__ __forceinline__ float h2f(unsigned short s) {
    return (float)__builtin_bit_cast(_Float16, s);
}

// ---------------- K1m: rfft over W via f16 MFMA (scale 1/128) ---------------
// Row-folded square GEMM: M=128 rows = {Yr[0..64], Yi[1..63]}, K=128, N=768.
// A (twiddles) in registers: r<65: cos(2pi r w/128)/128 ; r>=65: -sin(2pi (r-64) w/128)/128
// grid (B*H = 512), block 256 (4 waves M-split, 32 rows each).
// LDS: Xt[64][136] f16 (c_local x w, w lane-major scatter) = 17,408 B.
constexpr int K1PAD = 136;
__global__ __launch_bounds__(BDIM, 1) void k1m(const float* __restrict__ x,
                                               unsigned short* __restrict__ Rr,
                                               unsigned short* __restrict__ Ri) {
    __shared__ unsigned short Xt[64][K1PAD];
    const int tid = threadIdx.x;
    const int lane = tid & 63;
    const int wv = tid >> 6;
    const int b = blockIdx.x >> 7, h = blockIdx.x & 127;
    const float* xp = x + ((size_t)(b * 16384 + h * 128)) * 768;   // + w*768 + c
    const size_t sbase = ((size_t)(b * WM) * 128 + h) * 768;       // + wm*98304 + c

    // ---- per-lane twiddle A-fragments (registers only)
    f16x8 Af[2][4];
    {
        const int rlo = wv * 32 + (lane & 15);
        #pragma unroll
        for (int rf = 0; rf < 2; ++rf) {
            const int r = rlo + rf * 16;
            const int m = (r < 65) ? r : (r - 64);
            #pragma unroll
            for (int ks = 0; ks < 4; ++ks) {
                f16x8 v;
                #pragma unroll
                for (int j = 0; j < 8; ++j) {
                    int k = ks * 32 + ((lane >> 4) << 3) + j;
                    float th = (float)((m * k) & 127) * 0.04908738521234052f;
                    float s, c; __sincosf(th, &s, &c);
                    v[j] = (_Float16)(((r < 65) ? c : -s) * 0.0078125f);
                }
                Af[rf][ks] = v;
            }
        }
    }

    // ---- prefetch tile 0: w = tid&127, cg = tid>>7; 8 float4 = 32 c's
    const int w = tid & 127, cg = tid >> 7;
    float4 pfv[8];
    #pragma unroll
    for (int q = 0; q < 8; ++q)
        pfv[q] = *(const float4*)(xp + (size_t)w * 768 + cg * 32 + q * 4);

    const int koff = (lane >> 4) << 3;

    for (int t = 0; t < 12; ++t) {
        // ---- scatter staged regs into LDS [c_local][w] (w lane-major: 2-way free)
        #pragma unroll
        for (int q = 0; q < 8; ++q) {
            float4 v = pfv[q];
            int cb = cg * 32 + q * 4;
            Xt[cb + 0][w] = f2h(v.x);
            Xt[cb + 1][w] = f2h(v.y);
            Xt[cb + 2][w] = f2h(v.z);
            Xt[cb + 3][w] = f2h(v.w);
        }
        // ---- issue next tile's loads (in flight during MFMA)
        if (t < 11) {
            #pragma unroll
            for (int q = 0; q < 8; ++q)
                pfv[q] = *(const float4*)(xp + (size_t)w * 768 + (t + 1) * 64 + cg * 32 + q * 4);
        }
        __syncthreads();

        // ---- MFMA: acc[rf][cf]
        f32x4 acc[2][4];
        #pragma unroll
        for (int rf = 0; rf < 2; ++rf)
            #pragma unroll
            for (int cf = 0; cf < 4; ++cf)
                acc[rf][cf] = (f32x4){0, 0, 0, 0};
        #pragma unroll
        for (int ks = 0; ks < 4; ++ks) {
            #pragma unroll
            for (int cf = 0; cf < 4; ++cf) {
                const int cl = cf * 16 + (lane & 15);
                f16x8 Bf = *(const f16x8*)(&Xt[cl][ks * 32 + koff]);
                #pragma unroll
                for (int rf = 0; rf < 2; ++rf)
                    acc[rf][cf] = __builtin_amdgcn_mfma_f32_16x16x32_f16(Af[rf][ks], Bf, acc[rf][cf], 0, 0, 0);
            }
        }
        // ---- store: rows <65 -> Rr[wm=r], rows >=65 -> Ri[wm=r-64]
        #pragma unroll
        for (int rf = 0; rf < 2; ++rf)
            #pragma unroll
            for (int cf = 0; cf < 4; ++cf) {
                int col = t * 64 + cf * 16 + (lane & 15);
                int r0 = wv * 32 + rf * 16 + ((lane >> 4) << 2);
                #pragma unroll
                for (int reg = 0; reg < 4; ++reg) {
                    int r = r0 + reg;
                    if (r < 65) {
                        Rr[sbase + (size_t)r * 98304 + col] = f2h(acc[rf][cf][reg]);
                        if (r == 0)  Ri[sbase + col] = 0;                       // Ri[DC] = 0
                        if (r == 64) Ri[sbase + (size_t)64 * 98304 + col] = 0;  // Ri[Nyq] = 0
                    } else {
                        Ri[sbase + (size_t)(r - 64) * 98304 + col] = f2h(acc[rf][cf][reg]);
                    }
                }
            }
        __syncthreads();   // LDS safe to overwrite next tile
    }
}

// ---------------- K2m: complex DFT over H via f16 MFMA ----------------------
// Y[h2][c] = sum_h F[h2][h] X[h][c];  fwd: Yr=C.Xr+S.Xi, Yi=C.Xi-S.Xr
//                                     inv: Yr=C.Xr-S.Xi, Yi=C.Xi+S.Xr
// grid (260 slabs, 2 c-halves), block 256 (4 waves M-split, 32 rows each).
// LDS: C[128][136], S[128][136], Xt_r[64][136], Xt_i[64][136] = 104,448 B
constexpr int TSTR = 136;
template <int INV>
__global__ __launch_bounds__(BDIM, 1) void k2m(unsigned short* __restrict__ Rr,
                                               unsigned short* __restrict__ Ri) {
    extern __shared__ unsigned short lds[];
    unsigned short* Ct = lds;                  // [128][TSTR]
    unsigned short* St = Ct + 128 * TSTR;
    unsigned short* Xtr = St + 128 * TSTR;     // [64][TSTR]
    unsigned short* Xti = Xtr + 64 * TSTR;

    const int tid = threadIdx.x;
    const int lane = tid & 63;
    const int wv = tid >> 6;
    const size_t rowbase = (size_t)blockIdx.x * 128 * 768;
    const int chalf = blockIdx.y * 384;

    // build twiddle tables (p = h2*h mod 128)
    for (int idx = tid; idx < 16384; idx += BDIM) {
        int h2 = idx >> 7, h = idx & 127;
        float th = (float)((h2 * h) & 127) * 0.04908738521234052f;  // 2pi/128
        float s, c; __sincosf(th, &s, &c);
        Ct[h2 * TSTR + h] = f2h(c);
        St[h2 * TSTR + h] = f2h(s);
    }

    const int hme = tid & 127, cgme = tid >> 7;   // staging: h = lane-major
    unsigned short pfs[8][8];
    #pragma unroll
    for (int p = 0; p < 8; ++p) {
        const unsigned short* src = (p >> 2) ? Ri : Rr;
        int c0 = chalf + ((p & 3) * 2 + cgme) * 8;
        *(u32x4*)&pfs[p][0] = *(const u32x4*)(src + rowbase + (size_t)hme * 768 + c0);
    }
    __syncthreads();   // twiddle tables ready

    const int arow0 = wv * 32 + (lane & 15);
    const int koff = (lane >> 4) * 8;

    for (int t = 0; t < 6; ++t) {
        // ---- scatter-transpose staged regs into LDS (h lane-major: conflict-free)
        #pragma unroll
        for (int p = 0; p < 8; ++p) {
            unsigned short* dst = (p >> 2) ? Xti : Xtr;
            int cl = ((p & 3) * 2 + cgme) * 8;
            #pragma unroll
            for (int j = 0; j < 8; ++j)
                dst[(cl + j) * TSTR + hme] = pfs[p][j];
        }
        // ---- issue next tile's global loads (in flight during compute)
        if (t < 5) {
            #pragma unroll
            for (int p = 0; p < 8; ++p) {
                const unsigned short* src = (p >> 2) ? Ri : Rr;
                int c0 = chalf + (t + 1) * 64 + ((p & 3) * 2 + cgme) * 8;
                *(u32x4*)&pfs[p][0] = *(const u32x4*)(src + rowbase + (size_t)hme * 768 + c0);
            }
        }
        __syncthreads();

        // ---- MFMA: acc[rf][cf], rf in {0,1} (row frags), cf in {0..3} (col frags)
        f32x4 accr[2][4], acci[2][4];
        #pragma unroll
        for (int rf = 0; rf < 2; ++rf)
            #pragma unroll
            for (int cf = 0; cf < 4; ++cf) {
                accr[rf][cf] = (f32x4){0, 0, 0, 0};
                acci[rf][cf] = (f32x4){0, 0, 0, 0};
            }
        #pragma unroll
        for (int ks = 0; ks < 4; ++ks) {
            f16x8 Cf[2], Sp[2], Sn[2];
            #pragma unroll
            for (int rf = 0; rf < 2; ++rf) {
                int off = (arow0 + rf * 16) * TSTR + ks * 32 + koff;
                Cf[rf] = *(const f16x8*)(Ct + off);
                f16x8 s = *(const f16x8*)(St + off);
                u32x4 u = __builtin_bit_cast(u32x4, s);
                u ^= 0x80008000u;
                Sp[rf] = s;
                Sn[rf] = __builtin_bit_cast(f16x8, u);
            }
            #pragma unroll
            for (int cf = 0; cf < 4; ++cf) {
                int boff = (cf * 16 + (lane & 15)) * TSTR + ks * 32 + koff;
                f16x8 Br = *(const f16x8*)(Xtr + boff);
                f16x8 Bi = *(const f16x8*)(Xti + boff);
                #pragma unroll
                for (int rf = 0; rf < 2; ++rf) {
                    accr[rf][cf] = __builtin_amdgcn_mfma_f32_16x16x32_f16(Cf[rf], Br, accr[rf][cf], 0, 0, 0);
                    accr[rf][cf] = __builtin_amdgcn_mfma_f32_16x16x32_f16(INV ? Sn[rf] : Sp[rf], Bi, accr[rf][cf], 0, 0, 0);
                    acci[rf][cf] = __builtin_amdgcn_mfma_f32_16x16x32_f16(Cf[rf], Bi, acci[rf][cf], 0, 0, 0);
                    acci[rf][cf] = __builtin_amdgcn_mfma_f32_16x16x32_f16(INV ? Sp[rf] : Sn[rf], Br, acci[rf][cf], 0, 0, 0);
                }
            }
        }
        // ---- store Y tile to global (f16 scalar scatter, 32B runs per 16 lanes)
        const int cbase = chalf + t * 64;
        #pragma unroll
        for (int rf = 0; rf < 2; ++rf)
            #pragma unroll
            for (int cf = 0; cf < 4; ++cf) {
                int c = cbase + cf * 16 + (lane & 15);
                int h2b = wv * 32 + rf * 16 + ((lane >> 4) << 2);
                #pragma unroll
                for (int reg = 0; reg < 4; ++reg) {
                    size_t a = rowbase + (size_t)(h2b + reg) * 768 + c;
                    Rr[a] = f2h(accr[rf][cf][reg]);
                    Ri[a] = f2h(acci[rf][cf][reg]);
                }
            }
        __syncthreads();   // LDS safe to overwrite next iteration
    }
}

// ---------------- K3: complex MLP via f16 MFMA, union LDS -------------------
// LDS union (79,872 B dynamic): prologue = WT[4][96][104] (weights, transposed);
// main loop = Xs[128][200] (augmented X / O1 bounce). 2 wg/CU.
constexpr int K3_TILES = 2;
__global__ __launch_bounds__(BDIM, 1) void k3_mlp(unsigned short* __restrict__ Rr,
                                                  unsigned short* __restrict__ Ri,
                                                  const float* __restrict__ w1,
                                                  const float* __restrict__ b1,
                                                  const float* __restrict__ w2,
                                                  const float* __restrict__ b2) {
    extern __shared__ char smem[];
    unsigned short* WT = (unsigned short*)smem;        // [mat][96][104] (prologue only)
    unsigned short* Xs = (unsigned short*)smem;        // [128][200] (main loop)

    const int tid = threadIdx.x;
    const int lane = tid & 63;
    const int w = tid >> 6;
    const int n0 = w * 48;
    const int blk = blockIdx.y;

    {
        const float* src0 = w1 + (size_t)blk * 9216;
        const float* src1 = w1 + (size_t)(8 + blk) * 9216;
        const float* src2 = w2 + (size_t)blk * 9216;
        const float* src3 = w2 + (size_t)(8 + blk) * 9216;
        for (int idx = tid; idx < 9216; idx += BDIM) {
            int k = idx / 96, n = idx % 96;
            int d = n * 104 + k;
            WT[d]             = f2h(src0[idx]);
            WT[9984 + d]      = f2h(src1[idx]);
            WT[2 * 9984 + d]  = f2h(src2[idx]);
            WT[3 * 9984 + d]  = f2h(src3[idx]);
        }
    }
    float bias1[3], bias2[3];
    #pragma unroll
    for (int c = 0; c < 3; ++c) {
        int n = n0 + c * 16 + (lane & 15);
        bias1[c] = (n < 96) ? b1[blk * 96 + n] : b1[768 + blk * 96 + (n - 96)];
        bias2[c] = (n < 96) ? b2[blk * 96 + n] : b2[768 + blk * 96 + (n - 96)];
    }
    __syncthreads();

    f16x8 Bf1[3][6], Bf2[3][6];
    #pragma unroll
    for (int c = 0; c < 3; ++c) {
        const int nq = (n0 + c * 16) < 96;
        const int nl = n0 + c * 16 + (lane & 15) - (nq ? 0 : 96);
        #pragma unroll
        for (int kit = 0; kit < 6; ++kit) {
            const int kq = kit < 3;
            const int kl = kit * 32 + ((lane >> 4) << 3) - (kq ? 0 : 96);
            const int quad = kq ? (nq ? 0 : 1) : (nq ? 1 : 0);
            const bool flip = (!kq) && nq;
            {
                f16x8 v = *(const f16x8*)(WT + quad * 9984 + nl * 104 + kl);
                if (flip) { u32x4 u = __builtin_bit_cast(u32x4, v); u ^= 0x80008000u; v = __builtin_bit_cast(f16x8, u); }
                Bf1[c][kit] = v;
            }
            {
                f16x8 v = *(const f16x8*)(WT + (2 + quad) * 9984 + nl * 104 + kl);
                if (flip) { u32x4 u = __builtin_bit_cast(u32x4, v); u ^= 0x80008000u; v = __builtin_bit_cast(f16x8, u); }
                Bf2[c][kit] = v;
            }
        }
    }
    __syncthreads();   // all lanes done reading WT; region becomes Xs

    const unsigned short* Xl = Xs + (lane & 15) * 200 + ((lane >> 4) << 3);
    const int rowoff = ((lane >> 4) << 2);

    for (int t = 0; t < K3_TILES; ++t) {
        const int pos0 = (blockIdx.x * K3_TILES + t) * 128;
        // 16-byte moves: 3072 iters x 8 shorts = full 128x192 augmented tile
        for (int idx = tid; idx < 3072; idx += BDIM) {
            int plane = idx / 1536, rem = idx % 1536;
            int row = rem / 12, ch = (rem % 12) * 8;
            const unsigned short* src = plane ? Ri : Rr;
            u32x4 v = *(const u32x4*)(src + (size_t)(pos0 + row) * 768 + blk * 96 + ch);
            *(u32x4*)(Xs + row * 200 + plane * 96 + ch) = v;
        }
        __syncthreads();

        f32x4 acc[8][3];
        #pragma unroll
        for (int r = 0; r < 8; ++r)
            #pragma unroll
            for (int c = 0; c < 3; ++c)
                acc[r][c] = (f32x4){bias1[c], bias1[c], bias1[c], bias1[c]};
        #pragma unroll
        for (int kit = 0; kit < 6; ++kit) {
            f16x8 A[8];
            #pragma unroll
            for (int r = 0; r < 8; ++r)
                A[r] = *(const f16x8*)(Xl + r * 3200 + kit * 32);
            #pragma unroll
            for (int r = 0; r < 8; ++r)
                #pragma unroll
                for (int c = 0; c < 3; ++c)
                    acc[r][c] = __builtin_amdgcn_mfma_f32_16x16x32_f16(A[r], Bf1[c][kit], acc[r][c], 0, 0, 0);
        }
        __syncthreads();
        #pragma unroll
        for (int r = 0; r < 8; ++r)
            #pragma unroll
            for (int c = 0; c < 3; ++c) {
                int ncol = n0 + c * 16 + (lane & 15);
                #pragma unroll
                for (int reg = 0; reg < 4; ++reg) {
                    int row = r * 16 + rowoff + reg;
                    Xs[row * 200 + ncol] = f2h(fmaxf(acc[r][c][reg], 0.f));
                }
            }
        __syncthreads();

        #pragma unroll
        for (int r = 0; r < 8; ++r)
            #pragma unroll
            for (int c = 0; c < 3; ++c)
                acc[r][c] = (f32x4){bias2[c], bias2[c], bias2[c], bias2[c]};
        #pragma unroll
        for (int kit = 0; kit < 6; ++kit) {
            f16x8 A[8];
            #pragma unroll
            for (int r = 0; r < 8; ++r)
                A[r] = *(const f16x8*)(Xl + r * 3200 + kit * 32);
            #pragma unroll
            for (int r = 0; r < 8; ++r)
                #pragma unroll
                for (int c = 0; c < 3; ++c)
                    acc[r][c] = __builtin_amdgcn_mfma_f32_16x16x32_f16(A[r], Bf2[c][kit], acc[r][c], 0, 0, 0);
        }
        #pragma unroll
        for (int r = 0; r < 8; ++r)
            #pragma unroll
            for (int c = 0; c < 3; ++c) {
                int ncol = n0 + c * 16 + (lane & 15);
                unsigned short* dst = (ncol < 96) ? Rr : Ri;
                int nch = (ncol < 96) ? ncol : ncol - 96;
                #pragma unroll
                for (int reg = 0; reg < 4; ++reg) {
                    int row = r * 16 + rowoff + reg;
                    float v = acc[r][c][reg];
                    v = (v > 0.01f) ? v - 0.01f : ((v < -0.01f) ? v + 0.01f : 0.f);
                    dst[(size_t)(pos0 + row) * 768 + blk * 96 + nch] = f2h(v);
                }
            }
        __syncthreads();
    }
}

// ---------------- K5m: c2r inverse over W via f16 MFMA + residual -----------
// out[w][c] = sum_{wm=0}^{64} Cw[w][wm] Xr[wm][c] + Sn[w][wm] Xi[wm][c] + x[w][c]
// Cw = a*cos(2pi w wm/128)/128, Sn = -a*sin(...)/128, a = 1 (DC/Nyq) else 2.
// grid (B*H = 512), block 256 (4 waves M-split). K = 65 padded to 96.
// LDS: Xt[2][64][104] f16 = 26,624 B (c-local x wm, rows 65..95 zeroed).
constexpr int K5PAD = 104;
__global__ __launch_bounds__(BDIM, 1) void k5m(const unsigned short* __restrict__ Rr,
                                               const unsigned short* __restrict__ Ri,
                                               const float* __restrict__ x,
                                               float* __restrict__ out) {
    __shared__ unsigned short Xt[2][64][K5PAD];
    const int tid = threadIdx.x;
    const int lane = tid & 63;
    const int wv = tid >> 6;
    const int b = blockIdx.x >> 7, h = blockIdx.x & 127;
    const size_t rowbase = ((size_t)(b * WM) * 128 + h) * 768;   // + wm*98304 + c
    const size_t obase = ((size_t)(b * 16384 + h * 128)) * 768;  // + w*768 + c

    f16x8 Ca[2][3], Sa[2][3];
    {
        const int wrow_lo = wv * 32 + (lane & 15);
        #pragma unroll
        for (int rf = 0; rf < 2; ++rf) {
            const int wrow = wrow_lo + rf * 16;
            #pragma unroll
            for (int ks = 0; ks < 3; ++ks) {
                f16x8 cv, sv;
                #pragma unroll
                for (int j = 0; j < 8; ++j) {
                    int wm = ks * 32 + ((lane >> 4) << 3) + j;
                    float alpha = (wm > 64) ? 0.f : ((wm == 0 || wm == 64) ? 1.f : 2.f);
                    float th = (float)((wrow * wm) & 127) * 0.04908738521234052f;
                    float s, c; __sincosf(th, &s, &c);
                    cv[j] = (_Float16)(alpha * 0.0078125f * c);
                    sv[j] = (_Float16)(-alpha * 0.0078125f * s);
                }
                Ca[rf][ks] = cv;
                Sa[rf][ks] = sv;
            }
        }
    }

    for (int idx = tid; idx < 2 * 64 * 31; idx += BDIM) {
        int plane = idx / (64 * 31), rem = idx % (64 * 31);
        int cl = rem / 31, wm = 65 + rem % 31;
        Xt[plane][cl][wm] = 0;
    }

    unsigned short pfs[4][8], pfn[8];
    #pragma unroll
    for (int i = 0; i < 4; ++i) {
        const unsigned short* src = (i >> 1) ? Ri : Rr;
        int grp = (i & 1) * 4 + wv;
        *(u32x4*)&pfs[i][0] = *(const u32x4*)(src + rowbase + (size_t)lane * 98304 + grp * 8);
    }
    if (tid < 16) {
        const unsigned short* src = (tid >> 3) ? Ri : Rr;
        *(u32x4*)&pfn[0] = *(const u32x4*)(src + rowbase + (size_t)64 * 98304 + (tid & 7) * 8);
    }

    for (int t = 0; t < 12; ++t) {
        #pragma unroll
        for (int i = 0; i < 4; ++i) {
            int plane = i >> 1, grp = (i & 1) * 4 + wv;
            #pragma unroll
            for (int j = 0; j < 8; ++j)
                Xt[plane][grp * 8 + j][lane] = pfs[i][j];
        }
        if (tid < 16) {
            int plane = tid >> 3, grp = tid & 7;
            #pragma unroll
            for (int j = 0; j < 8; ++j)
                Xt[plane][grp * 8 + j][64] = pfn[j];
        }
        if (t < 11) {
            #pragma unroll
            for (int i = 0; i < 4; ++i) {
                const unsigned short* src = (i >> 1) ? Ri : Rr;
                int grp = (i & 1) * 4 + wv;
                *(u32x4*)&pfs[i][0] = *(const u32x4*)(src + rowbase + (size_t)lane * 98304 + (t + 1) * 64 + grp * 8);
            }
            if (tid < 16) {
                const unsigned short* src = (tid >> 3) ? Ri : Rr;
                *(u32x4*)&pfn[0] = *(const u32x4*)(src + rowbase + (size_t)64 * 98304 + (t + 1) * 64 + (tid & 7) * 8);
            }
        }
        __syncthreads();

        f32x4 acc[2][4];
        #pragma unroll
        for (int rf = 0; rf < 2; ++rf)
            #pragma unroll
            for (int cf = 0; cf < 4; ++cf)
                acc[rf][cf] = (f32x4){0, 0, 0, 0};
        const int koff = (lane >> 4) << 3;
        #pragma unroll
        for (int ks = 0; ks < 3; ++ks) {
            #pragma unroll
            for (int cf = 0; cf < 4; ++cf) {
                const int cl = cf * 16 + (lane & 15);
                f16x8 Br = *(const f16x8*)(&Xt[0][cl][ks * 32 + koff]);
                f16x8 Bi = *(const f16x8*)(&Xt[1][cl][ks * 32 + koff]);
                #pragma unroll
                for (int rf = 0; rf < 2; ++rf) {
                    acc[rf][cf] = __builtin_amdgcn_mfma_f32_16x16x32_f16(Ca[rf][ks], Br, acc[rf][cf], 0, 0, 0);
                    acc[rf][cf] = __builtin_amdgcn_mfma_f32_16x16x32_f16(Sa[rf][ks], Bi, acc[rf][cf], 0, 0, 0);
                }
            }
        }
        #pragma unroll
        for (int rf = 0; rf < 2; ++rf)
            #pragma unroll
            for (int cf = 0; cf < 4; ++cf) {
                int col = t * 64 + cf * 16 + (lane & 15);
                int row0 = wv * 32 + rf * 16 + ((lane >> 4) << 2);
                #pragma unroll
                for (int reg = 0; reg < 4; ++reg) {
                    size_t a = obase + (size_t)(row0 + reg) * 768 + col;
                    out[a] = acc[rf][cf][reg] + x[a];
                }
            }
        __syncthreads();
    }
}

extern "C" void kernel_launch(void* const* d_in, const int* in_sizes, int n_in,
                              void* d_out, int out_size, void* d_ws, size_t ws_size,
                              hipStream_t stream) {
    const float* x  = (const float*)d_in[0];
    const float* w1 = (const float*)d_in[1];
    const float* b1 = (const float*)d_in[2];
    const float* w2 = (const float*)d_in[3];
    const float* b2 = (const float*)d_in[4];
    float* out = (float*)d_out;

    unsigned short* Rr = (unsigned short*)d_ws;
    unsigned short* Ri = Rr + NSPEC;

    const size_t k2lds = (size_t)(2 * 128 * TSTR + 2 * 64 * TSTR) * 2;  // 104,448 B
    const size_t k3lds = (size_t)4 * 96 * 104 * 2;                      // 79,872 B (union)

    k1m<<<dim3(512), BDIM, 0, stream>>>(x, Rr, Ri);
    k2m<0><<<dim3(260, 2), BDIM, k2lds, stream>>>(Rr, Ri);
    k3_mlp<<<dim3(130, 8), BDIM, k3lds, stream>>>(Rr, Ri, w1, b1, w2, b2);
    k2m<1><<<dim3(260, 2), BDIM, k2lds, stream>>>(Rr, Ri);
    k5m<<<dim3(512), BDIM, 0, stream>>>(Rr, Ri, x, out);
}

// Round 8
// 396.037 us; speedup vs baseline: 1.2821x; 1.2821x over previous
//
#include <hip/hip_runtime.h>
#include <hip/hip_bf16.h>

#define BDIM 256
constexpr int Bc = 4, Hc = 128, Wcn = 128, Cc = 768, WM = 65, NB = 8, BS = 96;
constexpr int NROWS = Bc * WM * Hc;              // 33280 spectral rows (b, wm, h)
constexpr size_t NSPEC = (size_t)NROWS * Cc;     // 25,559,040 elems per r/i plane

typedef __attribute__((ext_vector_type(8))) _Float16 f16x8;
typedef __attribute__((ext_vector_type(4))) float f32x4;
typedef __attribute__((ext_vector_type(4))) unsigned int u32x4;

__device__ __forceinline__ unsigned short f2h(float f) {
    return __builtin_bit_cast(unsigned short, (_Float16)f);
}
__device__ __forceinline__ float h2f(unsigned short s) {
    return (float)__builtin_bit_cast(_Float16, s);
}
// barrier that does NOT drain vmcnt: LDS coherence (lgkm) + s_barrier only.
__device__ __forceinline__ void barx() {
    asm volatile("s_waitcnt lgkmcnt(0)" ::: "memory");
    __builtin_amdgcn_s_barrier();
}

// ---------------- K1m: rfft over W via f16 MFMA (scale 1/128) ---------------
// Row-folded square GEMM: M=128 rows = {Yr[0..64], Yi[1..63]}, K=128, N=768.
// grid (B*H = 512), block 256 (4 waves M-split, 32 rows each).
constexpr int K1PAD = 136;
__global__ __launch_bounds__(BDIM, 1) void k1m(const float* __restrict__ x,
                                               unsigned short* __restrict__ Rr,
                                               unsigned short* __restrict__ Ri) {
    __shared__ unsigned short Xt[64][K1PAD];
    const int tid = threadIdx.x;
    const int lane = tid & 63;
    const int wv = tid >> 6;
    const int b = blockIdx.x >> 7, h = blockIdx.x & 127;
    const float* xp = x + ((size_t)(b * 16384 + h * 128)) * 768;   // + w*768 + c
    const size_t sbase = ((size_t)(b * WM) * 128 + h) * 768;       // + wm*98304 + c

    f16x8 Af[2][4];
    {
        const int rlo = wv * 32 + (lane & 15);
        #pragma unroll
        for (int rf = 0; rf < 2; ++rf) {
            const int r = rlo + rf * 16;
            const int m = (r < 65) ? r : (r - 64);
            #pragma unroll
            for (int ks = 0; ks < 4; ++ks) {
                f16x8 v;
                #pragma unroll
                for (int j = 0; j < 8; ++j) {
                    int k = ks * 32 + ((lane >> 4) << 3) + j;
                    float th = (float)((m * k) & 127) * 0.04908738521234052f;
                    float s, c; __sincosf(th, &s, &c);
                    v[j] = (_Float16)(((r < 65) ? c : -s) * 0.0078125f);
                }
                Af[rf][ks] = v;
            }
        }
    }

    const int w = tid & 127, cg = tid >> 7;
    float4 pfv[8];
    #pragma unroll
    for (int q = 0; q < 8; ++q)
        pfv[q] = *(const float4*)(xp + (size_t)w * 768 + cg * 32 + q * 4);

    const int koff = (lane >> 4) << 3;

    for (int t = 0; t < 12; ++t) {
        #pragma unroll
        for (int q = 0; q < 8; ++q) {
            float4 v = pfv[q];
            int cb = cg * 32 + q * 4;
            Xt[cb + 0][w] = f2h(v.x);
            Xt[cb + 1][w] = f2h(v.y);
            Xt[cb + 2][w] = f2h(v.z);
            Xt[cb + 3][w] = f2h(v.w);
        }
        if (t < 11) {
            #pragma unroll
            for (int q = 0; q < 8; ++q)
                pfv[q] = *(const float4*)(xp + (size_t)w * 768 + (t + 1) * 64 + cg * 32 + q * 4);
        }
        barx();

        f32x4 acc[2][4];
        #pragma unroll
        for (int rf = 0; rf < 2; ++rf)
            #pragma unroll
            for (int cf = 0; cf < 4; ++cf)
                acc[rf][cf] = (f32x4){0, 0, 0, 0};
        #pragma unroll
        for (int ks = 0; ks < 4; ++ks) {
            #pragma unroll
            for (int cf = 0; cf < 4; ++cf) {
                const int cl = cf * 16 + (lane & 15);
                f16x8 Bf = *(const f16x8*)(&Xt[cl][ks * 32 + koff]);
                #pragma unroll
                for (int rf = 0; rf < 2; ++rf)
                    acc[rf][cf] = __builtin_amdgcn_mfma_f32_16x16x32_f16(Af[rf][ks], Bf, acc[rf][cf], 0, 0, 0);
            }
        }
        #pragma unroll
        for (int rf = 0; rf < 2; ++rf)
            #pragma unroll
            for (int cf = 0; cf < 4; ++cf) {
                int col = t * 64 + cf * 16 + (lane & 15);
                int r0 = wv * 32 + rf * 16 + ((lane >> 4) << 2);
                #pragma unroll
                for (int reg = 0; reg < 4; ++reg) {
                    int r = r0 + reg;
                    if (r < 65) {
                        Rr[sbase + (size_t)r * 98304 + col] = f2h(acc[rf][cf][reg]);
                        if (r == 0)  Ri[sbase + col] = 0;
                        if (r == 64) Ri[sbase + (size_t)64 * 98304 + col] = 0;
                    } else {
                        Ri[sbase + (size_t)(r - 64) * 98304 + col] = f2h(acc[rf][cf][reg]);
                    }
                }
            }
        barx();
    }
}

// ---------------- K2m: complex DFT over H via f16 MFMA ----------------------
constexpr int TSTR = 136;
template <int INV>
__global__ __launch_bounds__(BDIM, 1) void k2m(unsigned short* __restrict__ Rr,
                                               unsigned short* __restrict__ Ri) {
    extern __shared__ unsigned short lds[];
    unsigned short* Ct = lds;                  // [128][TSTR]
    unsigned short* St = Ct + 128 * TSTR;
    unsigned short* Xtr = St + 128 * TSTR;     // [64][TSTR]
    unsigned short* Xti = Xtr + 64 * TSTR;

    const int tid = threadIdx.x;
    const int lane = tid & 63;
    const int wv = tid >> 6;
    const size_t rowbase = (size_t)blockIdx.x * 128 * 768;
    const int chalf = blockIdx.y * 384;

    for (int idx = tid; idx < 16384; idx += BDIM) {
        int h2 = idx >> 7, h = idx & 127;
        float th = (float)((h2 * h) & 127) * 0.04908738521234052f;  // 2pi/128
        float s, c; __sincosf(th, &s, &c);
        Ct[h2 * TSTR + h] = f2h(c);
        St[h2 * TSTR + h] = f2h(s);
    }

    const int hme = tid & 127, cgme = tid >> 7;
    unsigned short pfs[8][8];
    #pragma unroll
    for (int p = 0; p < 8; ++p) {
        const unsigned short* src = (p >> 2) ? Ri : Rr;
        int c0 = chalf + ((p & 3) * 2 + cgme) * 8;
        *(u32x4*)&pfs[p][0] = *(const u32x4*)(src + rowbase + (size_t)hme * 768 + c0);
    }
    barx();   // twiddle tables ready (lgkm only; prefetch stays in flight)

    const int arow0 = wv * 32 + (lane & 15);
    const int koff = (lane >> 4) * 8;

    for (int t = 0; t < 6; ++t) {
        #pragma unroll
        for (int p = 0; p < 8; ++p) {
            unsigned short* dst = (p >> 2) ? Xti : Xtr;
            int cl = ((p & 3) * 2 + cgme) * 8;
            #pragma unroll
            for (int j = 0; j < 8; ++j)
                dst[(cl + j) * TSTR + hme] = pfs[p][j];
        }
        if (t < 5) {
            #pragma unroll
            for (int p = 0; p < 8; ++p) {
                const unsigned short* src = (p >> 2) ? Ri : Rr;
                int c0 = chalf + (t + 1) * 64 + ((p & 3) * 2 + cgme) * 8;
                *(u32x4*)&pfs[p][0] = *(const u32x4*)(src + rowbase + (size_t)hme * 768 + c0);
            }
        }
        barx();

        f32x4 accr[2][4], acci[2][4];
        #pragma unroll
        for (int rf = 0; rf < 2; ++rf)
            #pragma unroll
            for (int cf = 0; cf < 4; ++cf) {
                accr[rf][cf] = (f32x4){0, 0, 0, 0};
                acci[rf][cf] = (f32x4){0, 0, 0, 0};
            }
        #pragma unroll
        for (int ks = 0; ks < 4; ++ks) {
            f16x8 Cf[2], Sp[2], Sn[2];
            #pragma unroll
            for (int rf = 0; rf < 2; ++rf) {
                int off = (arow0 + rf * 16) * TSTR + ks * 32 + koff;
                Cf[rf] = *(const f16x8*)(Ct + off);
                f16x8 s = *(const f16x8*)(St + off);
                u32x4 u = __builtin_bit_cast(u32x4, s);
                u ^= 0x80008000u;
                Sp[rf] = s;
                Sn[rf] = __builtin_bit_cast(f16x8, u);
            }
            #pragma unroll
            for (int cf = 0; cf < 4; ++cf) {
                int boff = (cf * 16 + (lane & 15)) * TSTR + ks * 32 + koff;
                f16x8 Br = *(const f16x8*)(Xtr + boff);
                f16x8 Bi = *(const f16x8*)(Xti + boff);
                #pragma unroll
                for (int rf = 0; rf < 2; ++rf) {
                    accr[rf][cf] = __builtin_amdgcn_mfma_f32_16x16x32_f16(Cf[rf], Br, accr[rf][cf], 0, 0, 0);
                    accr[rf][cf] = __builtin_amdgcn_mfma_f32_16x16x32_f16(INV ? Sn[rf] : Sp[rf], Bi, accr[rf][cf], 0, 0, 0);
                    acci[rf][cf] = __builtin_amdgcn_mfma_f32_16x16x32_f16(Cf[rf], Bi, acci[rf][cf], 0, 0, 0);
                    acci[rf][cf] = __builtin_amdgcn_mfma_f32_16x16x32_f16(INV ? Sp[rf] : Sn[rf], Br, acci[rf][cf], 0, 0, 0);
                }
            }
        }
        const int cbase = chalf + t * 64;
        #pragma unroll
        for (int rf = 0; rf < 2; ++rf)
            #pragma unroll
            for (int cf = 0; cf < 4; ++cf) {
                int c = cbase + cf * 16 + (lane & 15);
                int h2b = wv * 32 + rf * 16 + ((lane >> 4) << 2);
                #pragma unroll
                for (int reg = 0; reg < 4; ++reg) {
                    size_t a = rowbase + (size_t)(h2b + reg) * 768 + c;
                    Rr[a] = f2h(accr[rf][cf][reg]);
                    Ri[a] = f2h(acci[rf][cf][reg]);
                }
            }
        barx();
    }
}

// ---------------- K3 v3: complex MLP, persistent wgs + prefetch pipeline ----
// grid (32, 8): 256 wgs (1/CU), each owns tiles tau = wgx + 32k (8-9 tiles).
// Weight prologue once per wg. Union LDS: WT[4][96][104] -> Xs[128][200].
// Raw lgkm-only barriers keep next-tile global loads in flight across phases.
__global__ __launch_bounds__(BDIM, 1) void k3_mlp(unsigned short* __restrict__ Rr,
                                                  unsigned short* __restrict__ Ri,
                                                  const float* __restrict__ w1,
                                                  const float* __restrict__ b1,
                                                  const float* __restrict__ w2,
                                                  const float* __restrict__ b2) {
    extern __shared__ char smem[];
    unsigned short* WT = (unsigned short*)smem;        // [mat][96][104] (prologue)
    unsigned short* Xs = (unsigned short*)smem;        // [128][200] (main loop)

    const int tid = threadIdx.x;
    const int lane = tid & 63;
    const int w = tid >> 6;
    const int n0 = w * 48;
    const int blk = blockIdx.y;
    const int wgx = blockIdx.x;

    // per-thread staging geometry (loop-invariant): 12 x 16B moves cover the
    // 128x192 augmented tile.  goff = element offset within a tile slab
    // (plane folded in: Ri == Rr + NSPEC), ldsoff = dest offset in Xs.
    int goff[12], ldsoff[12];
    #pragma unroll
    for (int i = 0; i < 12; ++i) {
        int idx = tid + i * BDIM;
        int plane = idx / 1536, rem = idx % 1536;
        int row = rem / 12, ch = (rem % 12) * 8;
        goff[i] = row * 768 + blk * 96 + ch;           // + plane*NSPEC (size_t below)
        if (plane) goff[i] = -goff[i] - 1;             // tag plane in sign
        ldsoff[i] = row * 200 + plane * 96 + ch;
    }

    // ---- issue tile-0 prefetch FIRST (hides HBM latency under prologue)
    u32x4 pfs[12];
    {
        size_t tb = (size_t)wgx * 98304;
        #pragma unroll
        for (int i = 0; i < 12; ++i) {
            int g = goff[i];
            size_t a = (g >= 0) ? tb + g : tb + (size_t)(-g - 1) + NSPEC;
            pfs[i] = *(const u32x4*)(Rr + a);
        }
    }

    // ---- weight staging (transposed into WT)
    {
        const float* src0 = w1 + (size_t)blk * 9216;
        const float* src1 = w1 + (size_t)(8 + blk) * 9216;
        const float* src2 = w2 + (size_t)blk * 9216;
        const float* src3 = w2 + (size_t)(8 + blk) * 9216;
        for (int idx = tid; idx < 9216; idx += BDIM) {
            int k = idx / 96, n = idx % 96;
            int d = n * 104 + k;
            WT[d]             = f2h(src0[idx]);
            WT[9984 + d]      = f2h(src1[idx]);
            WT[2 * 9984 + d]  = f2h(src2[idx]);
            WT[3 * 9984 + d]  = f2h(src3[idx]);
        }
    }
    float bias1[3], bias2[3];
    #pragma unroll
    for (int c = 0; c < 3; ++c) {
        int n = n0 + c * 16 + (lane & 15);
        bias1[c] = (n < 96) ? b1[blk * 96 + n] : b1[768 + blk * 96 + (n - 96)];
        bias2[c] = (n < 96) ? b2[blk * 96 + n] : b2[768 + blk * 96 + (n - 96)];
    }
    barx();

    f16x8 Bf1[3][6], Bf2[3][6];
    #pragma unroll
    for (int c = 0; c < 3; ++c) {
        const int nq = (n0 + c * 16) < 96;
        const int nl = n0 + c * 16 + (lane & 15) - (nq ? 0 : 96);
        #pragma unroll
        for (int kit = 0; kit < 6; ++kit) {
            const int kq = kit < 3;
            const int kl = kit * 32 + ((lane >> 4) << 3) - (kq ? 0 : 96);
            const int quad = kq ? (nq ? 0 : 1) : (nq ? 1 : 0);
            const bool flip = (!kq) && nq;
            {
                f16x8 v = *(const f16x8*)(WT + quad * 9984 + nl * 104 + kl);
                if (flip) { u32x4 u = __builtin_bit_cast(u32x4, v); u ^= 0x80008000u; v = __builtin_bit_cast(f16x8, u); }
                Bf1[c][kit] = v;
            }
            {
                f16x8 v = *(const f16x8*)(WT + (2 + quad) * 9984 + nl * 104 + kl);
                if (flip) { u32x4 u = __builtin_bit_cast(u32x4, v); u ^= 0x80008000u; v = __builtin_bit_cast(f16x8, u); }
                Bf2[c][kit] = v;
            }
        }
    }
    barx();   // all lanes done reading WT; region becomes Xs

    const unsigned short* Xl = Xs + (lane & 15) * 200 + ((lane >> 4) << 3);
    const int rowoff = ((lane >> 4) << 2);

    for (int tau = wgx; tau < 260; tau += 32) {
        const int pos0 = tau * 128;
        // ---- scatter staged regs into Xs
        #pragma unroll
        for (int i = 0; i < 12; ++i)
            *(u32x4*)(Xs + ldsoff[i]) = pfs[i];
        // ---- issue next tile's loads (stay in flight through L1+relu+L2)
        {
            int taun = tau + 32;
            if (taun < 260) {
                size_t tb = (size_t)taun * 98304;
                #pragma unroll
                for (int i = 0; i < 12; ++i) {
                    int g = goff[i];
                    size_t a = (g >= 0) ? tb + g : tb + (size_t)(-g - 1) + NSPEC;
                    pfs[i] = *(const u32x4*)(Rr + a);
                }
            }
        }
        barx();

        // ---- layer 1
        f32x4 acc[8][3];
        #pragma unroll
        for (int r = 0; r < 8; ++r)
            #pragma unroll
            for (int c = 0; c < 3; ++c)
                acc[r][c] = (f32x4){bias1[c], bias1[c], bias1[c], bias1[c]};
        #pragma unroll
        for (int kit = 0; kit < 6; ++kit) {
            f16x8 A[8];
            #pragma unroll
            for (int r = 0; r < 8; ++r)
                A[r] = *(const f16x8*)(Xl + r * 3200 + kit * 32);
            #pragma unroll
            for (int r = 0; r < 8; ++r)
                #pragma unroll
                for (int c = 0; c < 3; ++c)
                    acc[r][c] = __builtin_amdgcn_mfma_f32_16x16x32_f16(A[r], Bf1[c][kit], acc[r][c], 0, 0, 0);
        }
        barx();
        // ---- ReLU -> O1 into Xs
        #pragma unroll
        for (int r = 0; r < 8; ++r)
            #pragma unroll
            for (int c = 0; c < 3; ++c) {
                int ncol = n0 + c * 16 + (lane & 15);
                #pragma unroll
                for (int reg = 0; reg < 4; ++reg) {
                    int row = r * 16 + rowoff + reg;
                    Xs[row * 200 + ncol] = f2h(fmaxf(acc[r][c][reg], 0.f));
                }
            }
        barx();

        // ---- layer 2
        #pragma unroll
        for (int r = 0; r < 8; ++r)
            #pragma unroll
            for (int c = 0; c < 3; ++c)
                acc[r][c] = (f32x4){bias2[c], bias2[c], bias2[c], bias2[c]};
        #pragma unroll
        for (int kit = 0; kit < 6; ++kit) {
            f16x8 A[8];
            #pragma unroll
            for (int r = 0; r < 8; ++r)
                A[r] = *(const f16x8*)(Xl + r * 3200 + kit * 32);
            #pragma unroll
            for (int r = 0; r < 8; ++r)
                #pragma unroll
                for (int c = 0; c < 3; ++c)
                    acc[r][c] = __builtin_amdgcn_mfma_f32_16x16x32_f16(A[r], Bf2[c][kit], acc[r][c], 0, 0, 0);
        }
        // ---- softshrink + scatter stores
        #pragma unroll
        for (int r = 0; r < 8; ++r)
            #pragma unroll
            for (int c = 0; c < 3; ++c) {
                int ncol = n0 + c * 16 + (lane & 15);
                unsigned short* dst = (ncol < 96) ? Rr : Ri;
                int nch = (ncol < 96) ? ncol : ncol - 96;
                #pragma unroll
                for (int reg = 0; reg < 4; ++reg) {
                    int row = r * 16 + rowoff + reg;
                    float v = acc[r][c][reg];
                    v = (v > 0.01f) ? v - 0.01f : ((v < -0.01f) ? v + 0.01f : 0.f);
                    dst[(size_t)(pos0 + row) * 768 + blk * 96 + nch] = f2h(v);
                }
            }
        barx();   // protect Xs before next tile's scatter
    }
}

// ---------------- K5m: c2r inverse over W via f16 MFMA + residual -----------
constexpr int K5PAD = 104;
__global__ __launch_bounds__(BDIM, 1) void k5m(const unsigned short* __restrict__ Rr,
                                               const unsigned short* __restrict__ Ri,
                                               const float* __restrict__ x,
                                               float* __restrict__ out) {
    __shared__ unsigned short Xt[2][64][K5PAD];
    const int tid = threadIdx.x;
    const int lane = tid & 63;
    const int wv = tid >> 6;
    const int b = blockIdx.x >> 7, h = blockIdx.x & 127;
    const size_t rowbase = ((size_t)(b * WM) * 128 + h) * 768;   // + wm*98304 + c
    const size_t obase = ((size_t)(b * 16384 + h * 128)) * 768;  // + w*768 + c

    f16x8 Ca[2][3], Sa[2][3];
    {
        const int wrow_lo = wv * 32 + (lane & 15);
        #pragma unroll
        for (int rf = 0; rf < 2; ++rf) {
            const int wrow = wrow_lo + rf * 16;
            #pragma unroll
            for (int ks = 0; ks < 3; ++ks) {
                f16x8 cv, sv;
                #pragma unroll
                for (int j = 0; j < 8; ++j) {
                    int wm = ks * 32 + ((lane >> 4) << 3) + j;
                    float alpha = (wm > 64) ? 0.f : ((wm == 0 || wm == 64) ? 1.f : 2.f);
                    float th = (float)((wrow * wm) & 127) * 0.04908738521234052f;
                    float s, c; __sincosf(th, &s, &c);
                    cv[j] = (_Float16)(alpha * 0.0078125f * c);
                    sv[j] = (_Float16)(-alpha * 0.0078125f * s);
                }
                Ca[rf][ks] = cv;
                Sa[rf][ks] = sv;
            }
        }
    }

    for (int idx = tid; idx < 2 * 64 * 31; idx += BDIM) {
        int plane = idx / (64 * 31), rem = idx % (64 * 31);
        int cl = rem / 31, wm = 65 + rem % 31;
        Xt[plane][cl][wm] = 0;
    }

    unsigned short pfs[4][8], pfn[8];
    #pragma unroll
    for (int i = 0; i < 4; ++i) {
        const unsigned short* src = (i >> 1) ? Ri : Rr;
        int grp = (i & 1) * 4 + wv;
        *(u32x4*)&pfs[i][0] = *(const u32x4*)(src + rowbase + (size_t)lane * 98304 + grp * 8);
    }
    if (tid < 16) {
        const unsigned short* src = (tid >> 3) ? Ri : Rr;
        *(u32x4*)&pfn[0] = *(const u32x4*)(src + rowbase + (size_t)64 * 98304 + (tid & 7) * 8);
    }

    for (int t = 0; t < 12; ++t) {
        #pragma unroll
        for (int i = 0; i < 4; ++i) {
            int plane = i >> 1, grp = (i & 1) * 4 + wv;
            #pragma unroll
            for (int j = 0; j < 8; ++j)
                Xt[plane][grp * 8 + j][lane] = pfs[i][j];
        }
        if (tid < 16) {
            int plane = tid >> 3, grp = tid & 7;
            #pragma unroll
            for (int j = 0; j < 8; ++j)
                Xt[plane][grp * 8 + j][64] = pfn[j];
        }
        if (t < 11) {
            #pragma unroll
            for (int i = 0; i < 4; ++i) {
                const unsigned short* src = (i >> 1) ? Ri : Rr;
                int grp = (i & 1) * 4 + wv;
                *(u32x4*)&pfs[i][0] = *(const u32x4*)(src + rowbase + (size_t)lane * 98304 + (t + 1) * 64 + grp * 8);
            }
            if (tid < 16) {
                const unsigned short* src = (tid >> 3) ? Ri : Rr;
                *(u32x4*)&pfn[0] = *(const u32x4*)(src + rowbase + (size_t)64 * 98304 + (t + 1) * 64 + (tid & 7) * 8);
            }
        }
        barx();

        f32x4 acc[2][4];
        #pragma unroll
        for (int rf = 0; rf < 2; ++rf)
            #pragma unroll
            for (int cf = 0; cf < 4; ++cf)
                acc[rf][cf] = (f32x4){0, 0, 0, 0};
        const int koff = (lane >> 4) << 3;
        #pragma unroll
        for (int ks = 0; ks < 3; ++ks) {
            #pragma unroll
            for (int cf = 0; cf < 4; ++cf) {
                const int cl = cf * 16 + (lane & 15);
                f16x8 Br = *(const f16x8*)(&Xt[0][cl][ks * 32 + koff]);
                f16x8 Bi = *(const f16x8*)(&Xt[1][cl][ks * 32 + koff]);
                #pragma unroll
                for (int rf = 0; rf < 2; ++rf) {
                    acc[rf][cf] = __builtin_amdgcn_mfma_f32_16x16x32_f16(Ca[rf][ks], Br, acc[rf][cf], 0, 0, 0);
                    acc[rf][cf] = __builtin_amdgcn_mfma_f32_16x16x32_f16(Sa[rf][ks], Bi, acc[rf][cf], 0, 0, 0);
                }
            }
        }
        #pragma unroll
        for (int rf = 0; rf < 2; ++rf)
            #pragma unroll
            for (int cf = 0; cf < 4; ++cf) {
                int col = t * 64 + cf * 16 + (lane & 15);
                int row0 = wv * 32 + rf * 16 + ((lane >> 4) << 2);
                #pragma unroll
                for (int reg = 0; reg < 4; ++reg) {
                    size_t a = obase + (size_t)(row0 + reg) * 768 + col;
                    out[a] = acc[rf][cf][reg] + x[a];
                }
            }
        barx();
    }
}

extern "C" void kernel_launch(void* const* d_in, const int* in_sizes, int n_in,
                              void* d_out, int out_size, void* d_ws, size_t ws_size,
                              hipStream_t stream) {
    const float* x  = (const float*)d_in[0];
    const float* w1 = (const float*)d_in[1];
    const float* b1 = (const float*)d_in[2];
    const float* w2 = (const float*)d_in[3];
    const float* b2 = (const float*)d_in[4];
    float* out = (float*)d_out;

    unsigned short* Rr = (unsigned short*)d_ws;
    unsigned short* Ri = Rr + NSPEC;

    const size_t k2lds = (size_t)(2 * 128 * TSTR + 2 * 64 * TSTR) * 2;  // 104,448 B
    const size_t k3lds = (size_t)4 * 96 * 104 * 2;                      // 79,872 B (union)

    k1m<<<dim3(512), BDIM, 0, stream>>>(x, Rr, Ri);
    k2m<0><<<dim3(260, 2), BDIM, k2lds, stream>>>(Rr, Ri);
    k3_mlp<<<dim3(32, 8), BDIM, k3lds, stream>>>(Rr, Ri, w1, b1, w2, b2);
    k2m<1><<<dim3(260, 2), BDIM, k2lds, stream>>>(Rr, Ri);
    k5m<<<dim3(512), BDIM, 0, stream>>>(Rr, Ri, x, out);
}

// Round 10
// 358.580 us; speedup vs baseline: 1.4161x; 1.1045x over previous
//
#include <hip/hip_runtime.h>
#include <hip/hip_bf16.h>

#define BDIM 256
constexpr int Bc = 4, Hc = 128, Wcn = 128, Cc = 768, WM = 65, NB = 8, BS = 96;
constexpr int NROWS = Bc * WM * Hc;              // 33280 spectral rows (b, wm, h)
constexpr size_t NSPEC = (size_t)NROWS * Cc;     // 25,559,040 elems per r/i plane

typedef __attribute__((ext_vector_type(8))) _Float16 f16x8;
typedef __attribute__((ext_vector_type(4))) float f32x4;
typedef __attribute__((ext_vector_type(4))) unsigned int u32x4;

__device__ __forceinline__ unsigned short f2h(float f) {
    return __builtin_bit_cast(unsigned short, (_Float16)f);
}
__device__ __forceinline__ float h2f(unsigned short s) {
    return (float)__builtin_bit_cast(_Float16, s);
}
// vmcnt-preserving barrier, FENCED: sched_barrier(0) + "memory" asm on BOTH
// sides so the machine scheduler cannot move any LDS op across s_barrier
// (raw s_barrier is not a compiler fence -- R9's replay race).
__device__ __forceinline__ void barx() {
    __builtin_amdgcn_sched_barrier(0);
    asm volatile("s_waitcnt lgkmcnt(0)" ::: "memory");
    __builtin_amdgcn_s_barrier();
    __builtin_amdgcn_sched_barrier(0);
    asm volatile("" ::: "memory");
}

// ---------------- Kprep: transpose MLP weights to f16 [mat][blk][n][k] ------
__global__ __launch_bounds__(BDIM) void kprep(const float* __restrict__ w1,
                                              const float* __restrict__ w2,
                                              unsigned short* __restrict__ WTg) {
    int idx = blockIdx.x * BDIM + threadIdx.x;   // 4*8*96*96 = 294,912
    if (idx >= 294912) return;
    int k = idx % 96, n = (idx / 96) % 96, blk = (idx / 9216) % 8, mat = idx / 73728;
    const float* src = (mat < 2) ? w1 : w2;
    int q = mat & 1;
    WTg[idx] = f2h(src[(((size_t)q * 8 + blk) * 96 + k) * 96 + n]);
}

// ---------------- K1m: rfft over W via f16 MFMA (scale 1/128) ---------------
// Row-folded square GEMM: M=128 rows = {Yr[0..64], Yi[1..63]}, K=128, N=768.
constexpr int K1PAD = 136;
__global__ __launch_bounds__(BDIM, 1) void k1m(const float* __restrict__ x,
                                               unsigned short* __restrict__ Rr,
                                               unsigned short* __restrict__ Ri) {
    __shared__ unsigned short Xt[64][K1PAD];
    const int tid = threadIdx.x;
    const int lane = tid & 63;
    const int wv = tid >> 6;
    const int b = blockIdx.x >> 7, h = blockIdx.x & 127;
    const float* xp = x + ((size_t)(b * 16384 + h * 128)) * 768;
    const size_t sbase = ((size_t)(b * WM) * 128 + h) * 768;

    f16x8 Af[2][4];
    {
        const int rlo = wv * 32 + (lane & 15);
        #pragma unroll
        for (int rf = 0; rf < 2; ++rf) {
            const int r = rlo + rf * 16;
            const int m = (r < 65) ? r : (r - 64);
            #pragma unroll
            for (int ks = 0; ks < 4; ++ks) {
                f16x8 v;
                #pragma unroll
                for (int j = 0; j < 8; ++j) {
                    int k = ks * 32 + ((lane >> 4) << 3) + j;
                    float th = (float)((m * k) & 127) * 0.04908738521234052f;
                    float s, c; __sincosf(th, &s, &c);
                    v[j] = (_Float16)(((r < 65) ? c : -s) * 0.0078125f);
                }
                Af[rf][ks] = v;
            }
        }
    }

    const int w = tid & 127, cg = tid >> 7;
    float4 pfv[8];
    #pragma unroll
    for (int q = 0; q < 8; ++q)
        pfv[q] = *(const float4*)(xp + (size_t)w * 768 + cg * 32 + q * 4);

    const int koff = (lane >> 4) << 3;

    for (int t = 0; t < 12; ++t) {
        #pragma unroll
        for (int q = 0; q < 8; ++q) {
            float4 v = pfv[q];
            int cb = cg * 32 + q * 4;
            Xt[cb + 0][w] = f2h(v.x);
            Xt[cb + 1][w] = f2h(v.y);
            Xt[cb + 2][w] = f2h(v.z);
            Xt[cb + 3][w] = f2h(v.w);
        }
        if (t < 11) {
            #pragma unroll
            for (int q = 0; q < 8; ++q)
                pfv[q] = *(const float4*)(xp + (size_t)w * 768 + (t + 1) * 64 + cg * 32 + q * 4);
        }
        barx();

        f32x4 acc[2][4];
        #pragma unroll
        for (int rf = 0; rf < 2; ++rf)
            #pragma unroll
            for (int cf = 0; cf < 4; ++cf)
                acc[rf][cf] = (f32x4){0, 0, 0, 0};
        #pragma unroll
        for (int ks = 0; ks < 4; ++ks) {
            #pragma unroll
            for (int cf = 0; cf < 4; ++cf) {
                const int cl = cf * 16 + (lane & 15);
                f16x8 Bf = *(const f16x8*)(&Xt[cl][ks * 32 + koff]);
                #pragma unroll
                for (int rf = 0; rf < 2; ++rf)
                    acc[rf][cf] = __builtin_amdgcn_mfma_f32_16x16x32_f16(Af[rf][ks], Bf, acc[rf][cf], 0, 0, 0);
            }
        }
        #pragma unroll
        for (int rf = 0; rf < 2; ++rf)
            #pragma unroll
            for (int cf = 0; cf < 4; ++cf) {
                int col = t * 64 + cf * 16 + (lane & 15);
                int r0 = wv * 32 + rf * 16 + ((lane >> 4) << 2);
                #pragma unroll
                for (int reg = 0; reg < 4; ++reg) {
                    int r = r0 + reg;
                    if (r < 65) {
                        Rr[sbase + (size_t)r * 98304 + col] = f2h(acc[rf][cf][reg]);
                        if (r == 0)  Ri[sbase + col] = 0;
                        if (r == 64) Ri[sbase + (size_t)64 * 98304 + col] = 0;
                    } else {
                        Ri[sbase + (size_t)(r - 64) * 98304 + col] = f2h(acc[rf][cf][reg]);
                    }
                }
            }
        barx();
    }
}

// ---------------- Kmid: fused fwd H-DFT -> complex MLP -> inv H-DFT ---------
// grid (260 slabs, 8 blocks). 256 threads / 4 waves. In-place on Rr/Ri.
// LDS (121,856 B dyn): Ct[128][136] | St[128][136] | Xt{r,i}[96][136]
//                       (Xt region reused as Y[128][200] for the MLP phases).
constexpr int KMT = 136;
__global__ __launch_bounds__(BDIM, 1) void kmid(unsigned short* __restrict__ Rr,
                                                unsigned short* __restrict__ Ri,
                                                const unsigned short* __restrict__ WTg,
                                                const float* __restrict__ b1,
                                                const float* __restrict__ b2) {
    extern __shared__ unsigned short lds[];
    unsigned short* Ct = lds;                    // [128][136]
    unsigned short* St = Ct + 128 * KMT;         // [128][136]
    unsigned short* Xtr = St + 128 * KMT;        // [96][136]
    unsigned short* Xti = Xtr + 96 * KMT;        // [96][136]
    unsigned short* Y   = Xtr;                   // [128][200] (union)

    const int tid = threadIdx.x;
    const int lane = tid & 63;
    const int wv = tid >> 6;
    const int s = blockIdx.x;
    const int blk = blockIdx.y;
    const size_t sbase = (size_t)s * 98304;      // slab base (128 rows x 768)

    // ---- issue X-tile loads (12 x 16B per thread; in flight under sincos)
    const int hme = tid & 127, cgme = tid >> 7;
    u32x4 pfs[12];
    #pragma unroll
    for (int p = 0; p < 12; ++p) {
        const unsigned short* src = (p >= 6) ? Ri : Rr;
        int cg = (p % 6) * 2 + cgme;
        pfs[p] = *(const u32x4*)(src + sbase + (size_t)hme * 768 + blk * 96 + cg * 8);
    }

    // ---- build twiddle tables (p = h2*h mod 128) — overlaps the loads
    for (int idx = tid; idx < 16384; idx += BDIM) {
        int h2 = idx >> 7, h = idx & 127;
        float th = (float)((h2 * h) & 127) * 0.04908738521234052f;
        float sv, cv; __sincosf(th, &sv, &cv);
        Ct[h2 * KMT + h] = f2h(cv);
        St[h2 * KMT + h] = f2h(sv);
    }

    // ---- biases
    const int n0 = wv * 48;
    float bias1[3], bias2[3];
    #pragma unroll
    for (int c = 0; c < 3; ++c) {
        int n = n0 + c * 16 + (lane & 15);
        bias1[c] = (n < 96) ? b1[blk * 96 + n] : b1[768 + blk * 96 + (n - 96)];
        bias2[c] = (n < 96) ? b2[blk * 96 + n] : b2[768 + blk * 96 + (n - 96)];
    }

    // ---- scatter X tile into Xt[c][h] (h lane-major: conflict-free)
    #pragma unroll
    for (int p = 0; p < 12; ++p) {
        unsigned short* dst = (p >= 6) ? Xti : Xtr;
        int cl = ((p % 6) * 2 + cgme) * 8;
        unsigned short tmp[8];
        *(u32x4*)&tmp[0] = pfs[p];
        #pragma unroll
        for (int j = 0; j < 8; ++j)
            dst[(cl + j) * KMT + hme] = tmp[j];
    }
    __syncthreads();   // #1: tables + X staged (nothing usefully in flight)

    const int arow0 = wv * 32 + (lane & 15);
    const int koff = (lane >> 4) << 3;
    const int rowoff = (lane >> 4) << 2;

    // ---- phase A: fwd H-DFT (Yr = C.Xr + S.Xi ; Yi = C.Xi - S.Xr)
    f32x4 accr[2][6], acci[2][6];
    #pragma unroll
    for (int rf = 0; rf < 2; ++rf)
        #pragma unroll
        for (int cf = 0; cf < 6; ++cf) {
            accr[rf][cf] = (f32x4){0, 0, 0, 0};
            acci[rf][cf] = (f32x4){0, 0, 0, 0};
        }
    #pragma unroll
    for (int ks = 0; ks < 4; ++ks) {
        f16x8 Cf[2], Sp[2], Sn[2];
        #pragma unroll
        for (int rf = 0; rf < 2; ++rf) {
            int off = (arow0 + rf * 16) * KMT + ks * 32 + koff;
            Cf[rf] = *(const f16x8*)(Ct + off);
            f16x8 sv = *(const f16x8*)(St + off);
            u32x4 u = __builtin_bit_cast(u32x4, sv);
            u ^= 0x80008000u;
            Sp[rf] = sv;
            Sn[rf] = __builtin_bit_cast(f16x8, u);
        }
        #pragma unroll
        for (int cf = 0; cf < 6; ++cf) {
            int boff = (cf * 16 + (lane & 15)) * KMT + ks * 32 + koff;
            f16x8 Br = *(const f16x8*)(Xtr + boff);
            f16x8 Bi = *(const f16x8*)(Xti + boff);
            #pragma unroll
            for (int rf = 0; rf < 2; ++rf) {
                accr[rf][cf] = __builtin_amdgcn_mfma_f32_16x16x32_f16(Cf[rf], Br, accr[rf][cf], 0, 0, 0);
                accr[rf][cf] = __builtin_amdgcn_mfma_f32_16x16x32_f16(Sp[rf], Bi, accr[rf][cf], 0, 0, 0);
                acci[rf][cf] = __builtin_amdgcn_mfma_f32_16x16x32_f16(Cf[rf], Bi, acci[rf][cf], 0, 0, 0);
                acci[rf][cf] = __builtin_amdgcn_mfma_f32_16x16x32_f16(Sn[rf], Br, acci[rf][cf], 0, 0, 0);
            }
        }
    }

    // ---- issue weight-fragment loads (used in phase B; overlap Y writes)
    f16x8 Bf1[3][6], Bf2[3][6];
    #pragma unroll
    for (int c = 0; c < 3; ++c) {
        const int nq = (n0 + c * 16) < 96;
        const int nl = n0 + c * 16 + (lane & 15) - (nq ? 0 : 96);
        #pragma unroll
        for (int kit = 0; kit < 6; ++kit) {
            const int kq = kit < 3;
            const int kl = kit * 32 + koff - (kq ? 0 : 96);
            const int quad = kq ? (nq ? 0 : 1) : (nq ? 1 : 0);
            const bool flip = (!kq) && nq;
            {
                f16x8 v = *(const f16x8*)(WTg + ((size_t)(quad * 8 + blk) * 96 + nl) * 96 + kl);
                if (flip) { u32x4 u = __builtin_bit_cast(u32x4, v); u ^= 0x80008000u; v = __builtin_bit_cast(f16x8, u); }
                Bf1[c][kit] = v;
            }
            {
                f16x8 v = *(const f16x8*)(WTg + ((size_t)((2 + quad) * 8 + blk) * 96 + nl) * 96 + kl);
                if (flip) { u32x4 u = __builtin_bit_cast(u32x4, v); u ^= 0x80008000u; v = __builtin_bit_cast(f16x8, u); }
                Bf2[c][kit] = v;
            }
        }
    }

    barx();   // #2: all Xt reads done; region becomes Y (weight loads in flight)
    // ---- write Y [pos][k] augmented (k<96 = real, k>=96 = imag)
    #pragma unroll
    for (int rf = 0; rf < 2; ++rf)
        #pragma unroll
        for (int cf = 0; cf < 6; ++cf) {
            int c = cf * 16 + (lane & 15);
            #pragma unroll
            for (int reg = 0; reg < 4; ++reg) {
                int row = wv * 32 + rf * 16 + rowoff + reg;
                Y[row * 200 + c]      = f2h(accr[rf][cf][reg]);
                Y[row * 200 + 96 + c] = f2h(acci[rf][cf][reg]);
            }
        }
    barx();   // #3: Y visible (weight loads still in flight)

    // ---- phase B: MLP layer 1
    const unsigned short* Xl = Y + (lane & 15) * 200 + ((lane >> 4) << 3);
    f32x4 acc[8][3];
    #pragma unroll
    for (int r = 0; r < 8; ++r)
        #pragma unroll
        for (int c = 0; c < 3; ++c)
            acc[r][c] = (f32x4){bias1[c], bias1[c], bias1[c], bias1[c]};
    #pragma unroll
    for (int kit = 0; kit < 6; ++kit) {
        f16x8 A[8];
        #pragma unroll
        for (int r = 0; r < 8; ++r)
            A[r] = *(const f16x8*)(Xl + r * 3200 + kit * 32);
        #pragma unroll
        for (int r = 0; r < 8; ++r)
            #pragma unroll
            for (int c = 0; c < 3; ++c)
                acc[r][c] = __builtin_amdgcn_mfma_f32_16x16x32_f16(A[r], Bf1[c][kit], acc[r][c], 0, 0, 0);
    }
    __syncthreads();   // #4: layer-1 A-reads done (vmem queue empty by now)
    #pragma unroll
    for (int r = 0; r < 8; ++r)
        #pragma unroll
        for (int c = 0; c < 3; ++c) {
            int ncol = n0 + c * 16 + (lane & 15);
            #pragma unroll
            for (int reg = 0; reg < 4; ++reg) {
                int row = r * 16 + rowoff + reg;
                Y[row * 200 + ncol] = f2h(fmaxf(acc[r][c][reg], 0.f));
            }
        }
    __syncthreads();   // #5: O1 visible

    // ---- layer 2 + softshrink
    #pragma unroll
    for (int r = 0; r < 8; ++r)
        #pragma unroll
        for (int c = 0; c < 3; ++c)
            acc[r][c] = (f32x4){bias2[c], bias2[c], bias2[c], bias2[c]};
    #pragma unroll
    for (int kit = 0; kit < 6; ++kit) {
        f16x8 A[8];
        #pragma unroll
        for (int r = 0; r < 8; ++r)
            A[r] = *(const f16x8*)(Xl + r * 3200 + kit * 32);
        #pragma unroll
        for (int r = 0; r < 8; ++r)
            #pragma unroll
            for (int c = 0; c < 3; ++c)
                acc[r][c] = __builtin_amdgcn_mfma_f32_16x16x32_f16(A[r], Bf2[c][kit], acc[r][c], 0, 0, 0);
    }
    __syncthreads();   // #6: layer-2 A-reads done; region becomes Xt again
    // ---- write O2 transposed into Xt[c][h2] with softshrink
    #pragma unroll
    for (int r = 0; r < 8; ++r)
        #pragma unroll
        for (int c = 0; c < 3; ++c) {
            int ncol = n0 + c * 16 + (lane & 15);
            unsigned short* dst = (ncol < 96) ? Xtr : Xti;
            int cc = (ncol < 96) ? ncol : ncol - 96;
            #pragma unroll
            for (int reg = 0; reg < 4; ++reg) {
                int row = r * 16 + rowoff + reg;
                float v = acc[r][c][reg];
                v = (v > 0.01f) ? v - 0.01f : ((v < -0.01f) ? v + 0.01f : 0.f);
                dst[cc * KMT + row] = f2h(v);
            }
        }
    __syncthreads();   // #7: O2t visible

    // ---- phase C: inverse H-DFT (Zr = C.Or - S.Oi ; Zi = C.Oi + S.Or)
    #pragma unroll
    for (int rf = 0; rf < 2; ++rf)
        #pragma unroll
        for (int cf = 0; cf < 6; ++cf) {
            accr[rf][cf] = (f32x4){0, 0, 0, 0};
            acci[rf][cf] = (f32x4){0, 0, 0, 0};
        }
    #pragma unroll
    for (int ks = 0; ks < 4; ++ks) {
        f16x8 Cf[2], Sp[2], Sn[2];
        #pragma unroll
        for (int rf = 0; rf < 2; ++rf) {
            int off = (arow0 + rf * 16) * KMT + ks * 32 + koff;
            Cf[rf] = *(const f16x8*)(Ct + off);
            f16x8 sv = *(const f16x8*)(St + off);
            u32x4 u = __builtin_bit_cast(u32x4, sv);
            u ^= 0x80008000u;
            Sp[rf] = sv;
            Sn[rf] = __builtin_bit_cast(f16x8, u);
        }
        #pragma unroll
        for (int cf = 0; cf < 6; ++cf) {
            int boff = (cf * 16 + (lane & 15)) * KMT + ks * 32 + koff;
            f16x8 Br = *(const f16x8*)(Xtr + boff);
            f16x8 Bi = *(const f16x8*)(Xti + boff);
            #pragma unroll
            for (int rf = 0; rf < 2; ++rf) {
                accr[rf][cf] = __builtin_amdgcn_mfma_f32_16x16x32_f16(Cf[rf], Br, accr[rf][cf], 0, 0, 0);
                accr[rf][cf] = __builtin_amdgcn_mfma_f32_16x16x32_f16(Sn[rf], Bi, accr[rf][cf], 0, 0, 0);
                acci[rf][cf] = __builtin_amdgcn_mfma_f32_16x16x32_f16(Cf[rf], Bi, acci[rf][cf], 0, 0, 0);
                acci[rf][cf] = __builtin_amdgcn_mfma_f32_16x16x32_f16(Sp[rf], Br, acci[rf][cf], 0, 0, 0);
            }
        }
    }
    // ---- store to global spectral planes (in place)
    #pragma unroll
    for (int rf = 0; rf < 2; ++rf)
        #pragma unroll
        for (int cf = 0; cf < 6; ++cf) {
            int c = blk * 96 + cf * 16 + (lane & 15);
            int h0 = wv * 32 + rf * 16 + rowoff;
            #pragma unroll
            for (int reg = 0; reg < 4; ++reg) {
                size_t a = sbase + (size_t)(h0 + reg) * 768 + c;
                Rr[a] = f2h(accr[rf][cf][reg]);
                Ri[a] = f2h(acci[rf][cf][reg]);
            }
        }
}

// ---------------- K5m: c2r inverse over W via f16 MFMA + residual -----------
constexpr int K5PAD = 104;
__global__ __launch_bounds__(BDIM, 1) void k5m(const unsigned short* __restrict__ Rr,
                                               const unsigned short* __restrict__ Ri,
                                               const float* __restrict__ x,
                                               float* __restrict__ out) {
    __shared__ unsigned short Xt[2][64][K5PAD];
    const int tid = threadIdx.x;
    const int lane = tid & 63;
    const int wv = tid >> 6;
    const int b = blockIdx.x >> 7, h = blockIdx.x & 127;
    const size_t rowbase = ((size_t)(b * WM) * 128 + h) * 768;
    const size_t obase = ((size_t)(b * 16384 + h * 128)) * 768;

    f16x8 Ca[2][3], Sa[2][3];
    {
        const int wrow_lo = wv * 32 + (lane & 15);
        #pragma unroll
        for (int rf = 0; rf < 2; ++rf) {
            const int wrow = wrow_lo + rf * 16;
            #pragma unroll
            for (int ks = 0; ks < 3; ++ks) {
                f16x8 cv, sv;
                #pragma unroll
                for (int j = 0; j < 8; ++j) {
                    int wm = ks * 32 + ((lane >> 4) << 3) + j;
                    float alpha = (wm > 64) ? 0.f : ((wm == 0 || wm == 64) ? 1.f : 2.f);
                    float th = (float)((wrow * wm) & 127) * 0.04908738521234052f;
                    float s, c; __sincosf(th, &s, &c);
                    cv[j] = (_Float16)(alpha * 0.0078125f * c);
                    sv[j] = (_Float16)(-alpha * 0.0078125f * s);
                }
                Ca[rf][ks] = cv;
                Sa[rf][ks] = sv;
            }
        }
    }

    for (int idx = tid; idx < 2 * 64 * 31; idx += BDIM) {
        int plane = idx / (64 * 31), rem = idx % (64 * 31);
        int cl = rem / 31, wm = 65 + rem % 31;
        Xt[plane][cl][wm] = 0;
    }

    unsigned short pfs[4][8], pfn[8];
    #pragma unroll
    for (int i = 0; i < 4; ++i) {
        const unsigned short* src = (i >> 1) ? Ri : Rr;
        int grp = (i & 1) * 4 + wv;
        *(u32x4*)&pfs[i][0] = *(const u32x4*)(src + rowbase + (size_t)lane * 98304 + grp * 8);
    }
    if (tid < 16) {
        const unsigned short* src = (tid >> 3) ? Ri : Rr;
        *(u32x4*)&pfn[0] = *(const u32x4*)(src + rowbase + (size_t)64 * 98304 + (tid & 7) * 8);
    }

    for (int t = 0; t < 12; ++t) {
        #pragma unroll
        for (int i = 0; i < 4; ++i) {
            int plane = i >> 1, grp = (i & 1) * 4 + wv;
            #pragma unroll
            for (int j = 0; j < 8; ++j)
                Xt[plane][grp * 8 + j][lane] = pfs[i][j];
        }
        if (tid < 16) {
            int plane = tid >> 3, grp = tid & 7;
            #pragma unroll
            for (int j = 0; j < 8; ++j)
                Xt[plane][grp * 8 + j][64] = pfn[j];
        }
        if (t < 11) {
            #pragma unroll
            for (int i = 0; i < 4; ++i) {
                const unsigned short* src = (i >> 1) ? Ri : Rr;
                int grp = (i & 1) * 4 + wv;
                *(u32x4*)&pfs[i][0] = *(const u32x4*)(src + rowbase + (size_t)lane * 98304 + (t + 1) * 64 + grp * 8);
            }
            if (tid < 16) {
                const unsigned short* src = (tid >> 3) ? Ri : Rr;
                *(u32x4*)&pfn[0] = *(const u32x4*)(src + rowbase + (size_t)64 * 98304 + (t + 1) * 64 + (tid & 7) * 8);
            }
        }
        barx();

        f32x4 acc[2][4];
        #pragma unroll
        for (int rf = 0; rf < 2; ++rf)
            #pragma unroll
            for (int cf = 0; cf < 4; ++cf)
                acc[rf][cf] = (f32x4){0, 0, 0, 0};
        const int koff = (lane >> 4) << 3;
        #pragma unroll
        for (int ks = 0; ks < 3; ++ks) {
            #pragma unroll
            for (int cf = 0; cf < 4; ++cf) {
                const int cl = cf * 16 + (lane & 15);
                f16x8 Br = *(const f16x8*)(&Xt[0][cl][ks * 32 + koff]);
                f16x8 Bi = *(const f16x8*)(&Xt[1][cl][ks * 32 + koff]);
                #pragma unroll
                for (int rf = 0; rf < 2; ++rf) {
                    acc[rf][cf] = __builtin_amdgcn_mfma_f32_16x16x32_f16(Ca[rf][ks], Br, acc[rf][cf], 0, 0, 0);
                    acc[rf][cf] = __builtin_amdgcn_mfma_f32_16x16x32_f16(Sa[rf][ks], Bi, acc[rf][cf], 0, 0, 0);
                }
            }
        }
        #pragma unroll
        for (int rf = 0; rf < 2; ++rf)
            #pragma unroll
            for (int cf = 0; cf < 4; ++cf) {
                int col = t * 64 + cf * 16 + (lane & 15);
                int row0 = wv * 32 + rf * 16 + ((lane >> 4) << 2);
                #pragma unroll
                for (int reg = 0; reg < 4; ++reg) {
                    size_t a = obase + (size_t)(row0 + reg) * 768 + col;
                    out[a] = acc[rf][cf][reg] + x[a];
                }
            }
        barx();
    }
}

extern "C" void kernel_launch(void* const* d_in, const int* in_sizes, int n_in,
                              void* d_out, int out_size, void* d_ws, size_t ws_size,
                              hipStream_t stream) {
    const float* x  = (const float*)d_in[0];
    const float* w1 = (const float*)d_in[1];
    const float* b1 = (const float*)d_in[2];
    const float* w2 = (const float*)d_in[3];
    const float* b2 = (const float*)d_in[4];
    float* out = (float*)d_out;

    unsigned short* Rr = (unsigned short*)d_ws;
    unsigned short* Ri = Rr + NSPEC;
    unsigned short* WTg = Ri + NSPEC;            // 294,912 f16 = 0.6 MB

    const size_t kmlds = (size_t)(2 * 128 * KMT + 2 * 96 * KMT) * 2;  // 121,856 B

    kprep<<<dim3(1152), BDIM, 0, stream>>>(w1, w2, WTg);
    k1m<<<dim3(512), BDIM, 0, stream>>>(x, Rr, Ri);
    kmid<<<dim3(260, 8), BDIM, kmlds, stream>>>(Rr, Ri, WTg, b1, b2);
    k5m<<<dim3(512), BDIM, 0, stream>>>(Rr, Ri, x, out);
}